// Round 10
// baseline (221.285 us; speedup 1.0000x reference)
//
#include <hip/hip_runtime.h>
#include <hip/hip_bf16.h>

// 2-layer GCN on MI355X.
// out[v] = dinv[v] * ( sum_{e: dst=v} g[src_e] + g[v] ) + b,  g = (x@W) * dinv[row]
// dinv[v] = rsqrt(indeg(v) + 1)
// CSR build = bucketed counting sort, ALL atomics in LDS (no device atomics).
// g1/g2 stored BF16. aggregate: half-wave pair-gather; FLAT 2-round-per-node
// schedule (r9 lesson: binary tail chained 3 extra latency rounds/node).
// GEMM: W in LDS, 4x8 per thread, 1-deep X prefetch.

#define FDIM 64    // HID_DIM == OUT_DIM
#define NPB  128   // nodes per bucket (dst >> 7)
#define MAXB1 800  // >= ceil(100000/128)=782

// bf16 helpers (bit-level; finite data only)
static __device__ __forceinline__ unsigned short f2bf(float f) {
    unsigned int u = __float_as_uint(f);
    unsigned int r = 0x7FFFu + ((u >> 16) & 1u);
    return (unsigned short)((u + r) >> 16);
}
static __device__ __forceinline__ float lof(unsigned int u) {   // low bf16 -> f32
    return __uint_as_float(u << 16);
}
static __device__ __forceinline__ float hif(unsigned int u) {   // high bf16 -> f32
    return __uint_as_float(u & 0xFFFF0000u);
}

// ---------------- phase 1a: per-block bucket histogram ----------------
__global__ __launch_bounds__(256) void bucket_hist(const int* __restrict__ dst, int E,
                                                   int B1, int chunk, int B0,
                                                   int* __restrict__ H) {
    __shared__ int hist[MAXB1];
    const int blk = blockIdx.x, t = threadIdx.x;
    for (int i = t; i < B1; i += 256) hist[i] = 0;
    __syncthreads();
    const int beg = blk * chunk, end = min(E, beg + chunk);
    for (int e = beg + t; e < end; e += 256) atomicAdd(&hist[dst[e] >> 7], 1);
    __syncthreads();
    for (int i = t; i < B1; i += 256) H[i * B0 + blk] = hist[i];  // bin-major
}

// ---------------- scan A: per-block sums over spans of 2048 ----------------
__global__ __launch_bounds__(256) void scanA(const int* __restrict__ a, int S,
                                             int* __restrict__ bs) {
    __shared__ int s[256];
    const int blk = blockIdx.x, t = threadIdx.x;
    const int base = blk * 2048 + t * 8;
    int sum = 0;
    #pragma unroll
    for (int j = 0; j < 8; ++j) { int idx = base + j; if (idx < S) sum += a[idx]; }
    s[t] = sum;
    __syncthreads();
    for (int off = 128; off > 0; off >>= 1) {
        if (t < off) s[t] += s[t + off];
        __syncthreads();
    }
    if (t == 0) bs[blk] = s[0];
}

// ---------------- scan B: exclusive scan of block sums (nB <= 512) ----------
__global__ __launch_bounds__(512) void scanB(int* __restrict__ bs, int nB) {
    __shared__ int s[512];
    const int t = threadIdx.x;
    int v = (t < nB) ? bs[t] : 0;
    s[t] = v;
    __syncthreads();
    for (int off = 1; off < 512; off <<= 1) {
        int x = s[t];
        int y = (t >= off) ? s[t - off] : 0;
        __syncthreads();
        s[t] = x + y;
        __syncthreads();
    }
    if (t < nB) bs[t] = s[t] - v;
}

// ---------------- scan C: in-place exclusive scan (span 2048/block) ---------
__global__ __launch_bounds__(256) void scanC(int* __restrict__ a, int S,
                                             const int* __restrict__ bs) {
    __shared__ int s[256];
    const int blk = blockIdx.x, t = threadIdx.x;
    const int base = blk * 2048 + t * 8;
    int v[8];
    int sum = 0;
    #pragma unroll
    for (int j = 0; j < 8; ++j) { int idx = base + j; v[j] = (idx < S) ? a[idx] : 0; sum += v[j]; }
    s[t] = sum;
    __syncthreads();
    const int own = sum;
    for (int off = 1; off < 256; off <<= 1) {
        int x = s[t];
        int y = (t >= off) ? s[t - off] : 0;
        __syncthreads();
        s[t] = x + y;
        __syncthreads();
    }
    int run = bs[blk] + s[t] - own;   // exclusive prefix for this thread's segment
    #pragma unroll
    for (int j = 0; j < 8; ++j) { int idx = base + j; if (idx < S) a[idx] = run; run += v[j]; }
}

// ------- phase 1b: scatter edges into bucket-grouped packed (dlow7,src) -----
__global__ __launch_bounds__(256) void bucket_scatter(const int* __restrict__ src,
                                                      const int* __restrict__ dst,
                                                      int E, int B1, int chunk, int B0,
                                                      const int* __restrict__ Hs,
                                                      int* __restrict__ pairs) {
    __shared__ int cur[MAXB1];
    const int blk = blockIdx.x, t = threadIdx.x;
    for (int i = t; i < B1; i += 256) cur[i] = Hs[i * B0 + blk];
    __syncthreads();
    const int beg = blk * chunk, end = min(E, beg + chunk);
    for (int e = beg + t; e < end; e += 256) {
        int d = dst[e];
        int pos = atomicAdd(&cur[d >> 7], 1);          // LDS atomic
        pairs[pos] = ((d & 127) << 17) | src[e];       // src < 2^17
    }
}

// ---------------- phase 2: per-bucket local counting sort -> CSR ------------
__global__ __launch_bounds__(256) void bucket_csr(const int* __restrict__ pairs,
                                                  const int* __restrict__ Hs,
                                                  int B0, int E, int N,
                                                  float* __restrict__ dinv,
                                                  int* __restrict__ rowStart,
                                                  int* __restrict__ srcSorted) {
    __shared__ int hist[NPB], pref[NPB], cur[NPB];
    const int b = blockIdx.x, t = threadIdx.x;
    const int B1 = gridDim.x;
    const int vbase = b * NPB;
    const int nv = min(NPB, N - vbase);
    const int estart = Hs[b * B0];
    const int eend = (b + 1 < B1) ? Hs[(b + 1) * B0] : E;

    if (t < NPB) hist[t] = 0;
    __syncthreads();
    for (int e = estart + t; e < eend; e += 256)
        atomicAdd(&hist[pairs[e] >> 17], 1);
    __syncthreads();

    if (t < NPB) pref[t] = hist[t];
    __syncthreads();
    for (int off = 1; off < NPB; off <<= 1) {
        int v = 0;
        if (t < NPB && t >= off) v = pref[t - off];
        __syncthreads();
        if (t < NPB) pref[t] += v;
        __syncthreads();
    }
    if (t < nv) {
        int ex = pref[t] - hist[t];          // exclusive prefix
        rowStart[vbase + t] = estart + ex;
        dinv[vbase + t] = rsqrtf((float)(hist[t] + 1));
        cur[t] = estart + ex;
    }
    if (b == B1 - 1 && t == 0) rowStart[N] = E;
    __syncthreads();
    for (int e = estart + t; e < eend; e += 256) {
        int p = pairs[e];
        int pos = atomicAdd(&cur[p >> 17], 1);       // LDS atomic
        srcSorted[pos] = p & 0x1FFFF;
    }
}

// ------- GEMM: W in LDS, 4 rows x 8 cols per thread, 1-deep X prefetch ------
template <int K>
__global__ __launch_bounds__(256, 4) void gemm_scale(const float* __restrict__ X,
                                                     const float* __restrict__ W,
                                                     const float* __restrict__ dinv,
                                                     unsigned short* __restrict__ G, int N) {
    __shared__ float Wl[K * FDIM];
    const int t = threadIdx.x;
    {
        const float4* Wv  = reinterpret_cast<const float4*>(W);
        float4*       Wlv = reinterpret_cast<float4*>(Wl);
        #pragma unroll
        for (int i = 0; i < (K * FDIM) / (256 * 4); ++i)
            Wlv[i * 256 + t] = Wv[i * 256 + t];
    }
    __syncthreads();

    const int cq = t & 7;                    // col-group: cols 8cq..8cq+7
    const int rg = t >> 3;                   // row-group: 4 rows
    const int r0 = blockIdx.x * 128 + rg * 4;
    if (r0 >= N) return;                     // no barriers below

    const int rA = r0;
    const int rB = min(r0 + 1, N - 1);
    const int rC = min(r0 + 2, N - 1);
    const int rD = min(r0 + 3, N - 1);
    const float4* xrA = reinterpret_cast<const float4*>(X + (size_t)rA * K);
    const float4* xrB = reinterpret_cast<const float4*>(X + (size_t)rB * K);
    const float4* xrC = reinterpret_cast<const float4*>(X + (size_t)rC * K);
    const float4* xrD = reinterpret_cast<const float4*>(X + (size_t)rD * K);

    float acc[4][8];
    #pragma unroll
    for (int i = 0; i < 4; ++i)
        #pragma unroll
        for (int c = 0; c < 8; ++c) acc[i][c] = 0.f;

    auto do_k4 = [&](int k4, float4 c0, float4 c1, float4 c2, float4 c3) {
        float xs0[4] = {c0.x, c0.y, c0.z, c0.w};
        float xs1[4] = {c1.x, c1.y, c1.z, c1.w};
        float xs2[4] = {c2.x, c2.y, c2.z, c2.w};
        float xs3[4] = {c3.x, c3.y, c3.z, c3.w};
        #pragma unroll
        for (int j = 0; j < 4; ++j) {
            const float4* wp = reinterpret_cast<const float4*>(Wl + (size_t)(4 * k4 + j) * FDIM + cq * 8);
            float4 w0 = wp[0], w1 = wp[1];
            float wv[8] = {w0.x, w0.y, w0.z, w0.w, w1.x, w1.y, w1.z, w1.w};
            #pragma unroll
            for (int c = 0; c < 8; ++c) {
                acc[0][c] += xs0[j] * wv[c];
                acc[1][c] += xs1[j] * wv[c];
                acc[2][c] += xs2[j] * wv[c];
                acc[3][c] += xs3[j] * wv[c];
            }
        }
    };

    float4 nA = xrA[0], nB = xrB[0], nC = xrC[0], nD = xrD[0];
    #pragma unroll 4
    for (int k4 = 0; k4 < K / 4 - 1; ++k4) {
        float4 cA = nA, cB = nB, cC = nC, cD = nD;
        nA = xrA[k4 + 1]; nB = xrB[k4 + 1]; nC = xrC[k4 + 1]; nD = xrD[k4 + 1];
        do_k4(k4, cA, cB, cC, cD);
    }
    do_k4(K / 4 - 1, nA, nB, nC, nD);

    #pragma unroll
    for (int i = 0; i < 4; ++i) {
        const int r = r0 + i;
        if (r < N) {
            const float dv = dinv[r];
            unsigned int p0 = f2bf(acc[i][0] * dv) | (f2bf(acc[i][1] * dv) << 16);
            unsigned int p1 = f2bf(acc[i][2] * dv) | (f2bf(acc[i][3] * dv) << 16);
            unsigned int p2 = f2bf(acc[i][4] * dv) | (f2bf(acc[i][5] * dv) << 16);
            unsigned int p3 = f2bf(acc[i][6] * dv) | (f2bf(acc[i][7] * dv) << 16);
            *reinterpret_cast<uint4*>(G + (size_t)r * FDIM + cq * 8) = make_uint4(p0, p1, p2, p3);
        }
    }
}

// ------- aggregate: wave/node, flat 2-round schedule --------------------------
// Round 1: ALL idx loads (15 predicated pairs + single) + self gather + next
//          node's rowStart. Round 2: ALL gathers. One waitcnt, dense sum.
// deg>=32 (~0.03% of nodes) drains via a chained 16-edge loop first.
#define GATHER2(ii, uu, off)  int ii = srcSorted[eb + 2*(off)]; \
                              unsigned int uu = Gu[(size_t)ii * 32 + fl];
// flat-path macros (named scalars; uniform exec-skip predication, no arrays)
#define FIDX(k)  int i##k = 0; if (P > (k)) i##k = srcSorted[eb + 2*(k)];
#define FGAT(k)  unsigned int u##k = 0u; if (P > (k)) u##k = Gu[(size_t)i##k * 32 + fl];
#define FSUM(k)  ax += lof(u##k); ay += hif(u##k);

__global__ __launch_bounds__(256, 4) void aggregate(const unsigned int* __restrict__ Gu,
                                                    const int* __restrict__ rowStart,
                                                    const int* __restrict__ srcSorted,
                                                    const float* __restrict__ dinv,
                                                    const float* __restrict__ bias,
                                                    float* __restrict__ OUT, int N, int doRelu) {
    const int lane   = threadIdx.x & 63;
    const int half   = lane >> 5;        // 0: even edges, 1: odd edges
    const int fl     = lane & 31;        // uint index within row (features 2fl,2fl+1)
    const int waveId = blockIdx.x * (blockDim.x >> 6) + (threadIdx.x >> 6);
    const int nWaves = gridDim.x * (blockDim.x >> 6);
    const float2 bv  = reinterpret_cast<const float2*>(bias)[fl];

    int v = waveId;
    if (v >= N) return;
    int beg = rowStart[v];
    int end = rowStart[v + 1];

    while (true) {
        // prefetch next node's rowStart (consumed next iteration)
        const int vn = v + nWaves;
        int begN = 0, endN = 0;
        if (vn < N) { begN = rowStart[vn]; endN = rowStart[vn + 1]; }

        // self gather: issue first (independent of indices)
        unsigned int su = 0u;
        if (half == 0) su = Gu[(size_t)v * 32 + fl];
        float ax, ay;

        int e = beg;
        // rare heavy nodes: chained 16-edge blocks until <=31 remain
        {
            float hx = 0.f, hy = 0.f;
            while (end - e >= 32) {
                const int eb = e + half;
                GATHER2(j0, w0, 0) GATHER2(j1, w1, 1) GATHER2(j2, w2, 2) GATHER2(j3, w3, 3)
                GATHER2(j4, w4, 4) GATHER2(j5, w5, 5) GATHER2(j6, w6, 6) GATHER2(j7, w7, 7)
                hx += ((lof(w0) + lof(w1)) + (lof(w2) + lof(w3)))
                    + ((lof(w4) + lof(w5)) + (lof(w6) + lof(w7)));
                hy += ((hif(w0) + hif(w1)) + (hif(w2) + hif(w3)))
                    + ((hif(w4) + hif(w5)) + (hif(w6) + hif(w7)));
                e += 16;
            }
            ax = hx; ay = hy;
        }

        // flat path: rem in 0..31 -> P pairs (0..15) + optional single
        const int rem = end - e;
        const int P = rem >> 1;
        const int eb = e + half;

        // round 1: all index loads (no consumption between)
        FIDX(0)  FIDX(1)  FIDX(2)  FIDX(3)  FIDX(4)  FIDX(5)  FIDX(6)  FIDX(7)
        FIDX(8)  FIDX(9)  FIDX(10) FIDX(11) FIDX(12) FIDX(13) FIDX(14)
        int is = 0; if (rem & 1) is = srcSorted[end - 1];

        // round 2: all gathers
        FGAT(0)  FGAT(1)  FGAT(2)  FGAT(3)  FGAT(4)  FGAT(5)  FGAT(6)  FGAT(7)
        FGAT(8)  FGAT(9)  FGAT(10) FGAT(11) FGAT(12) FGAT(13) FGAT(14)
        unsigned int us = 0u;
        if ((rem & 1) && half == 0) us = Gu[(size_t)is * 32 + fl];

        // dense sum (u=0 defaults make predication-free accumulation correct)
        ax += lof(su); ay += hif(su);
        ax += lof(us); ay += hif(us);
        FSUM(0)  FSUM(1)  FSUM(2)  FSUM(3)  FSUM(4)  FSUM(5)  FSUM(6)  FSUM(7)
        FSUM(8)  FSUM(9)  FSUM(10) FSUM(11) FSUM(12) FSUM(13) FSUM(14)

        // fold halves
        ax += __shfl_xor(ax, 32, 64);
        ay += __shfl_xor(ay, 32, 64);

        const float dv = dinv[v];
        float2 r;
        r.x = ax * dv + bv.x;
        r.y = ay * dv + bv.y;
        if (doRelu) { r.x = fmaxf(r.x, 0.f); r.y = fmaxf(r.y, 0.f); }
        if (half == 0)
            reinterpret_cast<float2*>(OUT + (size_t)v * FDIM)[fl] = r;

        if (vn >= N) break;
        v = vn; beg = begN; end = endN;
    }
}

extern "C" void kernel_launch(void* const* d_in, const int* in_sizes, int n_in,
                              void* d_out, int out_size, void* d_ws, size_t ws_size,
                              hipStream_t stream) {
    const float* x     = (const float*)d_in[0];
    const int*   edges = (const int*)d_in[1];   // int32 per harness contract
    const float* W1    = (const float*)d_in[2];
    const float* b1    = (const float*)d_in[3];
    const float* W2    = (const float*)d_in[4];
    const float* b2    = (const float*)d_in[5];
    float*       out   = (float*)d_out;

    const int N = in_sizes[0] / 128;   // 100000
    const int E = in_sizes[1] / 2;     // 1600000
    const int* srcIdx = edges;
    const int* dstIdx = edges + E;

    const int B1 = (N + NPB - 1) / NPB;         // 782 buckets
    const int B0 = 256;                          // phase-1 blocks
    const int chunk = (E + B0 - 1) / B0;         // 6250
    const int S  = B1 * B0;                      // scanned size (200192)
    const int nSB = (S + 2047) / 2048;           // 98 scan blocks (<=512)

    // workspace layout (256B aligned slices)
    char* ws = (char*)d_ws;
    size_t off = 0;
    auto alloc = [&](size_t bytes) { char* p = ws + off; off = (off + bytes + 255) & ~(size_t)255; return p; };
    float* dinv      = (float*)alloc((size_t)N * 4);
    int*   H         = (int*)  alloc((size_t)S * 4);
    int*   blockSums = (int*)  alloc(512 * 4);
    int*   rowStart  = (int*)  alloc((size_t)(N + 1) * 4);
    int*   srcSorted = (int*)  alloc((size_t)E * 4);
    unsigned short* g1 = (unsigned short*)alloc((size_t)N * FDIM * 2);  // bf16
    float* x2        = (float*)alloc((size_t)N * FDIM * 4);
    int*   pairs     = (int*)x2;        // alias: pairs dead before x2 written
    unsigned short* g2 = g1;            // g1 dead after first aggregate

    const int gT = (N + 127) / 128;   // 782 GEMM tiles (128 rows each)

    bucket_hist   <<<B0, 256, 0, stream>>>(dstIdx, E, B1, chunk, B0, H);
    scanA         <<<nSB, 256, 0, stream>>>(H, S, blockSums);
    scanB         <<<1, 512, 0, stream>>>(blockSums, nSB);
    scanC         <<<nSB, 256, 0, stream>>>(H, S, blockSums);
    bucket_scatter<<<B0, 256, 0, stream>>>(srcIdx, dstIdx, E, B1, chunk, B0, H, pairs);
    bucket_csr    <<<B1, 256, 0, stream>>>(pairs, H, B0, E, N, dinv, rowStart, srcSorted);

    gemm_scale<128><<<gT, 256, 0, stream>>>(x,  W1, dinv, g1, N);
    aggregate      <<<2048, 256, 0, stream>>>((const unsigned int*)g1, rowStart, srcSorted, dinv, b1, x2, N, 1);
    gemm_scale<64> <<<gT, 256, 0, stream>>>(x2, W2, dinv, g2, N);
    aggregate      <<<2048, 256, 0, stream>>>((const unsigned int*)g2, rowStart, srcSorted, dinv, b2, out, N, 0);
}

// Round 11
// 203.239 us; speedup vs baseline: 1.0888x; 1.0888x over previous
//
#include <hip/hip_runtime.h>
#include <hip/hip_bf16.h>

// 2-layer GCN on MI355X.
// out[v] = dinv[v] * ( sum_{e: dst=v} g[src_e] + g[v] ) + b,  g = (x@W) * dinv[row]
// dinv[v] = rsqrt(indeg(v) + 1)
// CSR build = bucketed counting sort, ALL atomics in LDS (no device atomics).
// g1/g2 stored BF16. aggregate: half-wave pair-gather; flat BRANCHLESS
// 2-round remainder (r10 lesson: predicated branches let the scheduler chain
// loads; clamp addresses + cndmask masks instead, keep ONE basic block).
// GEMM: W in LDS, 4x8 per thread, 1-deep X prefetch.

#define FDIM 64    // HID_DIM == OUT_DIM
#define NPB  128   // nodes per bucket (dst >> 7)
#define MAXB1 800  // >= ceil(100000/128)=782

// bf16 helpers (bit-level; finite data only)
static __device__ __forceinline__ unsigned short f2bf(float f) {
    unsigned int u = __float_as_uint(f);
    unsigned int r = 0x7FFFu + ((u >> 16) & 1u);
    return (unsigned short)((u + r) >> 16);
}
static __device__ __forceinline__ float lof(unsigned int u) {   // low bf16 -> f32
    return __uint_as_float(u << 16);
}
static __device__ __forceinline__ float hif(unsigned int u) {   // high bf16 -> f32
    return __uint_as_float(u & 0xFFFF0000u);
}

// ---------------- phase 1a: per-block bucket histogram ----------------
__global__ __launch_bounds__(256) void bucket_hist(const int* __restrict__ dst, int E,
                                                   int B1, int chunk, int B0,
                                                   int* __restrict__ H) {
    __shared__ int hist[MAXB1];
    const int blk = blockIdx.x, t = threadIdx.x;
    for (int i = t; i < B1; i += 256) hist[i] = 0;
    __syncthreads();
    const int beg = blk * chunk, end = min(E, beg + chunk);
    for (int e = beg + t; e < end; e += 256) atomicAdd(&hist[dst[e] >> 7], 1);
    __syncthreads();
    for (int i = t; i < B1; i += 256) H[i * B0 + blk] = hist[i];  // bin-major
}

// ---------------- scan A: per-block sums over spans of 2048 ----------------
__global__ __launch_bounds__(256) void scanA(const int* __restrict__ a, int S,
                                             int* __restrict__ bs) {
    __shared__ int s[256];
    const int blk = blockIdx.x, t = threadIdx.x;
    const int base = blk * 2048 + t * 8;
    int sum = 0;
    #pragma unroll
    for (int j = 0; j < 8; ++j) { int idx = base + j; if (idx < S) sum += a[idx]; }
    s[t] = sum;
    __syncthreads();
    for (int off = 128; off > 0; off >>= 1) {
        if (t < off) s[t] += s[t + off];
        __syncthreads();
    }
    if (t == 0) bs[blk] = s[0];
}

// ---------------- scan B: exclusive scan of block sums (nB <= 512) ----------
__global__ __launch_bounds__(512) void scanB(int* __restrict__ bs, int nB) {
    __shared__ int s[512];
    const int t = threadIdx.x;
    int v = (t < nB) ? bs[t] : 0;
    s[t] = v;
    __syncthreads();
    for (int off = 1; off < 512; off <<= 1) {
        int x = s[t];
        int y = (t >= off) ? s[t - off] : 0;
        __syncthreads();
        s[t] = x + y;
        __syncthreads();
    }
    if (t < nB) bs[t] = s[t] - v;
}

// ---------------- scan C: in-place exclusive scan (span 2048/block) ---------
__global__ __launch_bounds__(256) void scanC(int* __restrict__ a, int S,
                                             const int* __restrict__ bs) {
    __shared__ int s[256];
    const int blk = blockIdx.x, t = threadIdx.x;
    const int base = blk * 2048 + t * 8;
    int v[8];
    int sum = 0;
    #pragma unroll
    for (int j = 0; j < 8; ++j) { int idx = base + j; v[j] = (idx < S) ? a[idx] : 0; sum += v[j]; }
    s[t] = sum;
    __syncthreads();
    const int own = sum;
    for (int off = 1; off < 256; off <<= 1) {
        int x = s[t];
        int y = (t >= off) ? s[t - off] : 0;
        __syncthreads();
        s[t] = x + y;
        __syncthreads();
    }
    int run = bs[blk] + s[t] - own;   // exclusive prefix for this thread's segment
    #pragma unroll
    for (int j = 0; j < 8; ++j) { int idx = base + j; if (idx < S) a[idx] = run; run += v[j]; }
}

// ------- phase 1b: scatter edges into bucket-grouped packed (dlow7,src) -----
__global__ __launch_bounds__(256) void bucket_scatter(const int* __restrict__ src,
                                                      const int* __restrict__ dst,
                                                      int E, int B1, int chunk, int B0,
                                                      const int* __restrict__ Hs,
                                                      int* __restrict__ pairs) {
    __shared__ int cur[MAXB1];
    const int blk = blockIdx.x, t = threadIdx.x;
    for (int i = t; i < B1; i += 256) cur[i] = Hs[i * B0 + blk];
    __syncthreads();
    const int beg = blk * chunk, end = min(E, beg + chunk);
    for (int e = beg + t; e < end; e += 256) {
        int d = dst[e];
        int pos = atomicAdd(&cur[d >> 7], 1);          // LDS atomic
        pairs[pos] = ((d & 127) << 17) | src[e];       // src < 2^17
    }
}

// ---------------- phase 2: per-bucket local counting sort -> CSR ------------
__global__ __launch_bounds__(256) void bucket_csr(const int* __restrict__ pairs,
                                                  const int* __restrict__ Hs,
                                                  int B0, int E, int N,
                                                  float* __restrict__ dinv,
                                                  int* __restrict__ rowStart,
                                                  int* __restrict__ srcSorted) {
    __shared__ int hist[NPB], pref[NPB], cur[NPB];
    const int b = blockIdx.x, t = threadIdx.x;
    const int B1 = gridDim.x;
    const int vbase = b * NPB;
    const int nv = min(NPB, N - vbase);
    const int estart = Hs[b * B0];
    const int eend = (b + 1 < B1) ? Hs[(b + 1) * B0] : E;

    if (t < NPB) hist[t] = 0;
    __syncthreads();
    for (int e = estart + t; e < eend; e += 256)
        atomicAdd(&hist[pairs[e] >> 17], 1);
    __syncthreads();

    if (t < NPB) pref[t] = hist[t];
    __syncthreads();
    for (int off = 1; off < NPB; off <<= 1) {
        int v = 0;
        if (t < NPB && t >= off) v = pref[t - off];
        __syncthreads();
        if (t < NPB) pref[t] += v;
        __syncthreads();
    }
    if (t < nv) {
        int ex = pref[t] - hist[t];          // exclusive prefix
        rowStart[vbase + t] = estart + ex;
        dinv[vbase + t] = rsqrtf((float)(hist[t] + 1));
        cur[t] = estart + ex;
    }
    if (b == B1 - 1 && t == 0) rowStart[N] = E;
    __syncthreads();
    for (int e = estart + t; e < eend; e += 256) {
        int p = pairs[e];
        int pos = atomicAdd(&cur[p >> 17], 1);       // LDS atomic
        srcSorted[pos] = p & 0x1FFFF;
    }
}

// ------- GEMM: W in LDS, 4 rows x 8 cols per thread, 1-deep X prefetch ------
template <int K>
__global__ __launch_bounds__(256, 4) void gemm_scale(const float* __restrict__ X,
                                                     const float* __restrict__ W,
                                                     const float* __restrict__ dinv,
                                                     unsigned short* __restrict__ G, int N) {
    __shared__ float Wl[K * FDIM];
    const int t = threadIdx.x;
    {
        const float4* Wv  = reinterpret_cast<const float4*>(W);
        float4*       Wlv = reinterpret_cast<float4*>(Wl);
        #pragma unroll
        for (int i = 0; i < (K * FDIM) / (256 * 4); ++i)
            Wlv[i * 256 + t] = Wv[i * 256 + t];
    }
    __syncthreads();

    const int cq = t & 7;                    // col-group: cols 8cq..8cq+7
    const int rg = t >> 3;                   // row-group: 4 rows
    const int r0 = blockIdx.x * 128 + rg * 4;
    if (r0 >= N) return;                     // no barriers below

    const int rA = r0;
    const int rB = min(r0 + 1, N - 1);
    const int rC = min(r0 + 2, N - 1);
    const int rD = min(r0 + 3, N - 1);
    const float4* xrA = reinterpret_cast<const float4*>(X + (size_t)rA * K);
    const float4* xrB = reinterpret_cast<const float4*>(X + (size_t)rB * K);
    const float4* xrC = reinterpret_cast<const float4*>(X + (size_t)rC * K);
    const float4* xrD = reinterpret_cast<const float4*>(X + (size_t)rD * K);

    float acc[4][8];
    #pragma unroll
    for (int i = 0; i < 4; ++i)
        #pragma unroll
        for (int c = 0; c < 8; ++c) acc[i][c] = 0.f;

    auto do_k4 = [&](int k4, float4 c0, float4 c1, float4 c2, float4 c3) {
        float xs0[4] = {c0.x, c0.y, c0.z, c0.w};
        float xs1[4] = {c1.x, c1.y, c1.z, c1.w};
        float xs2[4] = {c2.x, c2.y, c2.z, c2.w};
        float xs3[4] = {c3.x, c3.y, c3.z, c3.w};
        #pragma unroll
        for (int j = 0; j < 4; ++j) {
            const float4* wp = reinterpret_cast<const float4*>(Wl + (size_t)(4 * k4 + j) * FDIM + cq * 8);
            float4 w0 = wp[0], w1 = wp[1];
            float wv[8] = {w0.x, w0.y, w0.z, w0.w, w1.x, w1.y, w1.z, w1.w};
            #pragma unroll
            for (int c = 0; c < 8; ++c) {
                acc[0][c] += xs0[j] * wv[c];
                acc[1][c] += xs1[j] * wv[c];
                acc[2][c] += xs2[j] * wv[c];
                acc[3][c] += xs3[j] * wv[c];
            }
        }
    };

    float4 nA = xrA[0], nB = xrB[0], nC = xrC[0], nD = xrD[0];
    #pragma unroll 4
    for (int k4 = 0; k4 < K / 4 - 1; ++k4) {
        float4 cA = nA, cB = nB, cC = nC, cD = nD;
        nA = xrA[k4 + 1]; nB = xrB[k4 + 1]; nC = xrC[k4 + 1]; nD = xrD[k4 + 1];
        do_k4(k4, cA, cB, cC, cD);
    }
    do_k4(K / 4 - 1, nA, nB, nC, nD);

    #pragma unroll
    for (int i = 0; i < 4; ++i) {
        const int r = r0 + i;
        if (r < N) {
            const float dv = dinv[r];
            unsigned int p0 = f2bf(acc[i][0] * dv) | (f2bf(acc[i][1] * dv) << 16);
            unsigned int p1 = f2bf(acc[i][2] * dv) | (f2bf(acc[i][3] * dv) << 16);
            unsigned int p2 = f2bf(acc[i][4] * dv) | (f2bf(acc[i][5] * dv) << 16);
            unsigned int p3 = f2bf(acc[i][6] * dv) | (f2bf(acc[i][7] * dv) << 16);
            *reinterpret_cast<uint4*>(G + (size_t)r * FDIM + cq * 8) = make_uint4(p0, p1, p2, p3);
        }
    }
}

// ------- aggregate: wave/node, flat BRANCHLESS 2-round remainder ------------
// Heavy (deg>32, rare) drains via chained 16-edge blocks. Remainder (0..32
// edges) = 16 pair-slots, ALL loads unconditional in one basic block:
//   idx   : srcSorted[min(eb+2k, last)]        (v_min address clamp)
//   sani  : q = (unsigned)i < N ? i : 0        (guards rem==0 poisoned read)
//   gather: always; mask at sum (cndmask).
#define GATHER2(ii, uu, off)  int ii = srcSorted[eb + 2*(off)]; \
                              unsigned int uu = Gu[(size_t)ii * 32 + fl];
#define FI(k) int i##k = srcSorted[min(eb2 + 2*(k), last)];
#define FG(k) unsigned int q##k = ((unsigned)i##k < (unsigned)N) ? (unsigned)i##k : 0u; \
              unsigned int u##k = Gu[(size_t)q##k * 32 + fl];
#define FS(k) { unsigned int m##k = (eb2 + 2*(k) < end) ? u##k : 0u; \
                ax += lof(m##k); ay += hif(m##k); }

__global__ __launch_bounds__(256, 4) void aggregate(const unsigned int* __restrict__ Gu,
                                                    const int* __restrict__ rowStart,
                                                    const int* __restrict__ srcSorted,
                                                    const float* __restrict__ dinv,
                                                    const float* __restrict__ bias,
                                                    float* __restrict__ OUT, int N, int doRelu) {
    const int lane   = threadIdx.x & 63;
    const int half   = lane >> 5;        // 0: even edges, 1: odd edges
    const int fl     = lane & 31;        // uint index within row (features 2fl,2fl+1)
    const int waveId = blockIdx.x * (blockDim.x >> 6) + (threadIdx.x >> 6);
    const int nWaves = gridDim.x * (blockDim.x >> 6);
    const float2 bv  = reinterpret_cast<const float2*>(bias)[fl];

    int v = waveId;
    if (v >= N) return;
    int beg = rowStart[v];
    int end = rowStart[v + 1];

    while (true) {
        // prefetch next node's rowStart (consumed next iteration)
        const int vn = v + nWaves;
        int begN = 0, endN = 0;
        if (vn < N) { begN = rowStart[vn]; endN = rowStart[vn + 1]; }

        // self gather (independent of indices)
        unsigned int su = 0u;
        if (half == 0) su = Gu[(size_t)v * 32 + fl];

        float ax = 0.f, ay = 0.f;
        int e = beg;

        // rare heavy nodes: chained 16-edge blocks until <=32 remain
        while (end - e > 32) {
            const int eb = e + half;
            GATHER2(j0, w0, 0) GATHER2(j1, w1, 1) GATHER2(j2, w2, 2) GATHER2(j3, w3, 3)
            GATHER2(j4, w4, 4) GATHER2(j5, w5, 5) GATHER2(j6, w6, 6) GATHER2(j7, w7, 7)
            ax += ((lof(w0) + lof(w1)) + (lof(w2) + lof(w3)))
                + ((lof(w4) + lof(w5)) + (lof(w6) + lof(w7)));
            ay += ((hif(w0) + hif(w1)) + (hif(w2) + hif(w3)))
                + ((hif(w4) + hif(w5)) + (hif(w6) + hif(w7)));
            e += 16;
        }

        // flat branchless remainder: 16 pair-slots cover 0..32 edges
        const int last = end - 1;          // may be < e when rem==0 (sanitized)
        const int eb2 = e + half;

        // round 1: ALL index loads (unconditional, clamped)
        FI(0)  FI(1)  FI(2)  FI(3)  FI(4)  FI(5)  FI(6)  FI(7)
        FI(8)  FI(9)  FI(10) FI(11) FI(12) FI(13) FI(14) FI(15)

        // round 2: ALL gathers (unconditional, sanitized indices)
        FG(0)  FG(1)  FG(2)  FG(3)  FG(4)  FG(5)  FG(6)  FG(7)
        FG(8)  FG(9)  FG(10) FG(11) FG(12) FG(13) FG(14) FG(15)

        // masked sum (cndmask, no branches)
        ax += lof(su); ay += hif(su);
        FS(0)  FS(1)  FS(2)  FS(3)  FS(4)  FS(5)  FS(6)  FS(7)
        FS(8)  FS(9)  FS(10) FS(11) FS(12) FS(13) FS(14) FS(15)

        // fold halves
        ax += __shfl_xor(ax, 32, 64);
        ay += __shfl_xor(ay, 32, 64);

        const float dv = dinv[v];
        float2 r;
        r.x = ax * dv + bv.x;
        r.y = ay * dv + bv.y;
        if (doRelu) { r.x = fmaxf(r.x, 0.f); r.y = fmaxf(r.y, 0.f); }
        if (half == 0)
            reinterpret_cast<float2*>(OUT + (size_t)v * FDIM)[fl] = r;

        if (vn >= N) break;
        v = vn; beg = begN; end = endN;
    }
}

extern "C" void kernel_launch(void* const* d_in, const int* in_sizes, int n_in,
                              void* d_out, int out_size, void* d_ws, size_t ws_size,
                              hipStream_t stream) {
    const float* x     = (const float*)d_in[0];
    const int*   edges = (const int*)d_in[1];   // int32 per harness contract
    const float* W1    = (const float*)d_in[2];
    const float* b1    = (const float*)d_in[3];
    const float* W2    = (const float*)d_in[4];
    const float* b2    = (const float*)d_in[5];
    float*       out   = (float*)d_out;

    const int N = in_sizes[0] / 128;   // 100000
    const int E = in_sizes[1] / 2;     // 1600000
    const int* srcIdx = edges;
    const int* dstIdx = edges + E;

    const int B1 = (N + NPB - 1) / NPB;         // 782 buckets
    const int B0 = 256;                          // phase-1 blocks
    const int chunk = (E + B0 - 1) / B0;         // 6250
    const int S  = B1 * B0;                      // scanned size (200192)
    const int nSB = (S + 2047) / 2048;           // 98 scan blocks (<=512)

    // workspace layout (256B aligned slices)
    char* ws = (char*)d_ws;
    size_t off = 0;
    auto alloc = [&](size_t bytes) { char* p = ws + off; off = (off + bytes + 255) & ~(size_t)255; return p; };
    float* dinv      = (float*)alloc((size_t)N * 4);
    int*   H         = (int*)  alloc((size_t)S * 4);
    int*   blockSums = (int*)  alloc(512 * 4);
    int*   rowStart  = (int*)  alloc((size_t)(N + 1) * 4);
    int*   srcSorted = (int*)  alloc((size_t)E * 4);
    unsigned short* g1 = (unsigned short*)alloc((size_t)N * FDIM * 2);  // bf16
    float* x2        = (float*)alloc((size_t)N * FDIM * 4);
    int*   pairs     = (int*)x2;        // alias: pairs dead before x2 written
    unsigned short* g2 = g1;            // g1 dead after first aggregate

    const int gT = (N + 127) / 128;   // 782 GEMM tiles (128 rows each)

    bucket_hist   <<<B0, 256, 0, stream>>>(dstIdx, E, B1, chunk, B0, H);
    scanA         <<<nSB, 256, 0, stream>>>(H, S, blockSums);
    scanB         <<<1, 512, 0, stream>>>(blockSums, nSB);
    scanC         <<<nSB, 256, 0, stream>>>(H, S, blockSums);
    bucket_scatter<<<B0, 256, 0, stream>>>(srcIdx, dstIdx, E, B1, chunk, B0, H, pairs);
    bucket_csr    <<<B1, 256, 0, stream>>>(pairs, H, B0, E, N, dinv, rowStart, srcSorted);

    gemm_scale<128><<<gT, 256, 0, stream>>>(x,  W1, dinv, g1, N);
    aggregate      <<<2048, 256, 0, stream>>>((const unsigned int*)g1, rowStart, srcSorted, dinv, b1, x2, N, 1);
    gemm_scale<64> <<<gT, 256, 0, stream>>>(x2, W2, dinv, g2, N);
    aggregate      <<<2048, 256, 0, stream>>>((const unsigned int*)g2, rowStart, srcSorted, dinv, b2, out, N, 0);
}